// Round 6
// baseline (226.250 us; speedup 1.0000x reference)
//
#include <hip/hip_runtime.h>
#include <math.h>

#define B_   4
#define C_   256
#define CQK  32
#define N_   4096
#define TQ   32
#define TM   64
#define ITERS (N_ / TM)
#define PSS  72   // ps row stride (shorts)
#define NST  34   // proj LDS col stride (floats)

typedef __attribute__((ext_vector_type(8))) short short8;
typedef __attribute__((ext_vector_type(4))) short short4v;
typedef __attribute__((ext_vector_type(4))) float f32x4;
typedef __attribute__((ext_vector_type(2))) float f32x2;
typedef __attribute__((ext_vector_type(2))) unsigned int uint2v;

__device__ __forceinline__ unsigned short f2bf(float f) {
    unsigned u = __builtin_bit_cast(unsigned, f);
    u += 0x7fffu + ((u >> 16) & 1u);
    return (unsigned short)(u >> 16);
}

// ---------- weights -> bf16 [320][256] + fp32 bias[320] ----------
__global__ __launch_bounds__(256) void cvt_w(
    const float* __restrict__ Wq, const float* __restrict__ bq,
    const float* __restrict__ Wk, const float* __restrict__ bk,
    const float* __restrict__ Wv, const float* __restrict__ bv,
    unsigned short* __restrict__ wbf, float* __restrict__ biasf)
{
    const int r = blockIdx.x;   // 0..319
    const int t = threadIdx.x;
    const float* src = (r < 32) ? (Wq + r * C_)
                     : (r < 64) ? (Wk + (r - 32) * C_)
                                : (Wv + (r - 64) * C_);
    wbf[r * C_ + t] = f2bf(src[t]);
    if (t == 0)
        biasf[r] = (r < 32) ? bq[r] : (r < 64) ? bk[r - 32] : bv[r - 64];
}

// ---------- fused qkv projection: M=320, K=256, N=32/block ----------
// grid (N/32=128, B), 512 threads (8 waves). Wave (mi=w>>1, ni=w&1):
// M rows 80*mi..+79 (5 tiles), n = 16*ni..+15.
__global__ __launch_bounds__(512) void proj_qkv(
    const float* __restrict__ x, const unsigned short* __restrict__ wbf,
    const float* __restrict__ biasf,
    unsigned short* __restrict__ qb, unsigned short* __restrict__ kb,
    unsigned short* __restrict__ vb)
{
    __shared__ __align__(16) float xs[C_ * NST];   // 34.8 KB, [c][n] fp32

    const int t    = threadIdx.x;
    const int w    = t >> 6;
    const int lane = t & 63;
    const int quad = lane >> 4;
    const int c16  = lane & 15;
    const int n0   = blockIdx.x * 32;
    const int b    = blockIdx.y;
    const int mi   = w >> 1, ni = w & 1;

    // ---- stage x[b][0..255][n0..n0+31] -> LDS (coalesced float2 loads)
    {
        const int a = t & 15;       // n-slot: n = 2a, 2a+1
        const int cb = t >> 4;      // 32 c rows per pass
#pragma unroll
        for (int p = 0; p < 8; ++p) {
            const int c = 32 * p + cb;
            const f32x2 v = *(const f32x2*)&x[((size_t)(b * C_) + c) * N_ + n0 + 2 * a];
            *(f32x2*)&xs[c * NST + 2 * a] = v;
        }
    }
    __syncthreads();

    f32x4 acc[5];
#pragma unroll
    for (int i = 0; i < 5; ++i) acc[i] = (f32x4){0.f, 0.f, 0.f, 0.f};

    const unsigned short* wrow0 = wbf + (size_t)(80 * mi + c16) * C_ + quad * 8;

#pragma unroll
    for (int ks = 0; ks < 8; ++ks) {
        short8 af[5];
#pragma unroll
        for (int i = 0; i < 5; ++i)
            af[i] = *(const short8*)(wrow0 + (size_t)(16 * i) * C_ + 32 * ks);
        short8 bf;
#pragma unroll
        for (int j = 0; j < 8; ++j) {
            const float xv = xs[(32 * ks + 8 * quad + j) * NST + 16 * ni + c16];
            bf[j] = (short)f2bf(xv);
        }
#pragma unroll
        for (int i = 0; i < 5; ++i)
            acc[i] = __builtin_amdgcn_mfma_f32_16x16x32_bf16(af[i], bf, acc[i], 0, 0, 0);
    }

    // ---- epilogue
#pragma unroll
    for (int i = 0; i < 5; ++i) {
        const int OT = 5 * mi + i;
        const int obase = OT * 16 + 4 * quad;
        const f32x4 bv4 = *(const f32x4*)&biasf[obase];
        const int n = n0 + 16 * ni + c16;
        float vals[4];
#pragma unroll
        for (int r = 0; r < 4; ++r) vals[r] = acc[i][r] + bv4[r];
        if (OT < 4) {  // q (OT 0,1) / k (OT 2,3): [b][n][32]
            unsigned short* dst = (OT < 2) ? qb : kb;
            const int o = obase - ((OT < 2) ? 0 : 32);
            short4v pk;
#pragma unroll
            for (int r = 0; r < 4; ++r) pk[r] = (short)f2bf(vals[r]);
            *(short4v*)&dst[((size_t)(b * N_) + n) * 32 + o] = pk;
        } else {       // v: [b][c][n]
#pragma unroll
            for (int r = 0; r < 4; ++r) {
                const int c = obase + r - 64;
                vb[((size_t)(b * C_) + c) * N_ + n] = f2bf(vals[r]);
            }
        }
    }
}

// ---------- flash attention: 4 waves, 2 blocks/CU, XCD batch affinity ----------
// 1-D grid of 512: b = flat&3 (XCD-affine), q0 = (flat>>2)*32
__global__ __launch_bounds__(256) void attn_kernel(
    const float* __restrict__ x,
    const unsigned short* __restrict__ qg,
    const unsigned short* __restrict__ kg,
    const unsigned short* __restrict__ vg,
    float* __restrict__ out)
{
    __shared__ __align__(16) unsigned short ps[2][TQ * PSS];  // 9.2 KB
    __shared__ float ls[4 * TQ];

    const int t    = threadIdx.x;
    const int w    = t >> 6;        // 0..3: S-phase kv-tile AND PV-phase c-group
    const int lane = t & 63;
    const int quad = lane >> 4;
    const int c16  = lane & 15;
    const int flat = blockIdx.x;
    const int b    = flat & 3;
    const int q0   = (flat >> 2) * TQ;

    const unsigned short* kbase = kg + (size_t)(b * N_) * 32;
    const unsigned short* vbase = vg + (size_t)(b * C_) * N_;

    // hoist Q B-frags (iter-invariant): q-tiles g=0,1
    const short8 bq0 = *(const short8*)(qg + ((size_t)(b * N_) + q0 + c16) * 32 + quad * 8);
    const short8 bq1 = *(const short8*)(qg + ((size_t)(b * N_) + q0 + 16 + c16) * 32 + quad * 8);

    // prefetch K frag + V frags for iter 0
    short8 ak = *(const short8*)(kbase + (size_t)(w * 16 + c16) * 32 + quad * 8);
    short8 av[2][4];
#pragma unroll
    for (int s = 0; s < 2; ++s)
#pragma unroll
        for (int ct = 0; ct < 4; ++ct)
            av[s][ct] = *(const short8*)(
                vbase + (size_t)(64 * w + 16 * ct + c16) * N_ + 32 * s + 8 * quad);

    f32x4 O[4][2];
#pragma unroll
    for (int ct = 0; ct < 4; ++ct)
#pragma unroll
        for (int qt = 0; qt < 2; ++qt) O[ct][qt] = (f32x4){0.f, 0.f, 0.f, 0.f};

    float l0 = 0.f, l1 = 0.f;
    int buf = 0;

#pragma unroll 1
    for (int it = 0; it < ITERS; ++it) {
        // ---- S^T = K.Q^T (lane: kv = 16w+4quad+r, q = 16g+c16)
        const f32x4 z = {0.f, 0.f, 0.f, 0.f};
        const f32x4 s0 = __builtin_amdgcn_mfma_f32_16x16x32_bf16(ak, bq0, z, 0, 0, 0);
        const f32x4 s1 = __builtin_amdgcn_mfma_f32_16x16x32_bf16(ak, bq1, z, 0, 0, 0);

        // ---- prefetch next chunk (completed by the barrier's vmcnt drain)
        short8 akn, avn[2][4];
        if (it < ITERS - 1) {
            const int kvn = (it + 1) * TM;
            akn = *(const short8*)(kbase + (size_t)(kvn + w * 16 + c16) * 32 + quad * 8);
#pragma unroll
            for (int s = 0; s < 2; ++s)
#pragma unroll
                for (int ct = 0; ct < 4; ++ct)
                    avn[s][ct] = *(const short8*)(
                        vbase + (size_t)(64 * w + 16 * ct + c16) * N_ + kvn + 32 * s + 8 * quad);
        }

        // ---- exp (fixed m=0), partial sums, pack P^T -> LDS
        float p0[4], p1[4];
        float rs0 = 0.f, rs1 = 0.f;
#pragma unroll
        for (int r = 0; r < 4; ++r) {
            p0[r] = __expf(s0[r]); rs0 += p0[r];
            p1[r] = __expf(s1[r]); rs1 += p1[r];
        }
        rs0 += __shfl_xor(rs0, 16); rs0 += __shfl_xor(rs0, 32);
        rs1 += __shfl_xor(rs1, 16); rs1 += __shfl_xor(rs1, 32);
        l0 += rs0; l1 += rs1;

        uint2v u0, u1;
        u0.x = (unsigned)f2bf(p0[0]) | ((unsigned)f2bf(p0[1]) << 16);
        u0.y = (unsigned)f2bf(p0[2]) | ((unsigned)f2bf(p0[3]) << 16);
        u1.x = (unsigned)f2bf(p1[0]) | ((unsigned)f2bf(p1[1]) << 16);
        u1.y = (unsigned)f2bf(p1[2]) | ((unsigned)f2bf(p1[3]) << 16);
        const int kvc = w * 16 + 4 * quad;
        *(uint2v*)&ps[buf][(c16) * PSS + kvc]      = u0;
        *(uint2v*)&ps[buf][(16 + c16) * PSS + kvc] = u1;

        __syncthreads();

        // ---- PV: O^T[c][q] += V^T[c][kv] . P^T[kv][q]; wave owns c 64w..+63
        short8 bp[2][2];
#pragma unroll
        for (int qt = 0; qt < 2; ++qt)
#pragma unroll
            for (int s = 0; s < 2; ++s)
                bp[qt][s] = *(const short8*)&ps[buf][(16 * qt + c16) * PSS + 32 * s + 8 * quad];

#pragma unroll
        for (int s = 0; s < 2; ++s)
#pragma unroll
            for (int ct = 0; ct < 4; ++ct) {
                O[ct][0] = __builtin_amdgcn_mfma_f32_16x16x32_bf16(av[s][ct], bp[0][s], O[ct][0], 0, 0, 0);
                O[ct][1] = __builtin_amdgcn_mfma_f32_16x16x32_bf16(av[s][ct], bp[1][s], O[ct][1], 0, 0, 0);
            }

        ak = akn;
#pragma unroll
        for (int s = 0; s < 2; ++s)
#pragma unroll
            for (int ct = 0; ct < 4; ++ct) av[s][ct] = avn[s][ct];
        buf ^= 1;
    }

    if (quad == 0) {
        ls[w * TQ + c16]      = l0;
        ls[w * TQ + 16 + c16] = l1;
    }
    __syncthreads();

    // ---- epilogue: out = x + O / l
#pragma unroll
    for (int qt = 0; qt < 2; ++qt) {
        const int q = 16 * qt + c16;
        const float li = 1.0f / (ls[q] + ls[TQ + q] + ls[2 * TQ + q] + ls[3 * TQ + q]);
        const int n = q0 + q;
#pragma unroll
        for (int ct = 0; ct < 4; ++ct) {
#pragma unroll
            for (int r = 0; r < 4; ++r) {
                const int c = 64 * w + 16 * ct + 4 * quad + r;
                const size_t idx = ((size_t)(b * C_) + c) * N_ + n;
                out[idx] = x[idx] + O[ct][qt][r] * li;
            }
        }
    }
}

extern "C" void kernel_launch(void* const* d_in, const int* in_sizes, int n_in,
                              void* d_out, int out_size, void* d_ws, size_t ws_size,
                              hipStream_t stream) {
    const float* x  = (const float*)d_in[0];
    const float* Wq = (const float*)d_in[1];
    const float* bq = (const float*)d_in[2];
    const float* Wk = (const float*)d_in[3];
    const float* bk = (const float*)d_in[4];
    const float* Wv = (const float*)d_in[5];
    const float* bv = (const float*)d_in[6];
    float* out = (float*)d_out;

    unsigned short* ws16 = (unsigned short*)d_ws;
    unsigned short* qb  = ws16;                              // [B][N][32]  1 MB
    unsigned short* kb  = qb + (size_t)B_ * N_ * 32;         // [B][N][32]  1 MB
    unsigned short* vb  = kb + (size_t)B_ * N_ * 32;         // [B][C][N]   8 MB
    unsigned short* wbf = vb + (size_t)B_ * C_ * N_;         // [320][256] bf16
    float* biasf = (float*)(wbf + 320 * C_);                 // [320] fp32

    cvt_w<<<dim3(320), 256, 0, stream>>>(Wq, bq, Wk, bk, Wv, bv, wbf, biasf);
    proj_qkv<<<dim3(N_ / 32, B_), 512, 0, stream>>>(x, wbf, biasf, qb, kb, vb);
    attn_kernel<<<dim3(512), 256, 0, stream>>>(x, qb, kb, vb, out);
}

// Round 7
// 222.314 us; speedup vs baseline: 1.0177x; 1.0177x over previous
//
#include <hip/hip_runtime.h>
#include <math.h>

#define B_   4
#define C_   256
#define CQK  32
#define N_   4096
#define TQ   32
#define TM   64
#define ITERS (N_ / TM)
#define PSS  72   // ps row stride (shorts)

typedef __attribute__((ext_vector_type(8))) short short8;
typedef __attribute__((ext_vector_type(4))) short short4v;
typedef __attribute__((ext_vector_type(4))) float f32x4;
typedef __attribute__((ext_vector_type(2))) unsigned int uint2v;

#if __has_builtin(__builtin_amdgcn_exp2f)
#define EXP2F(x) __builtin_amdgcn_exp2f(x)
#else
#define EXP2F(x) exp2f(x)
#endif

__device__ __forceinline__ unsigned short f2bf(float f) {
    unsigned u = __builtin_bit_cast(unsigned, f);
    u += 0x7fffu + ((u >> 16) & 1u);
    return (unsigned short)(u >> 16);
}

// pack bf16(a) into low16, bf16(b) into high16 (round-half-up)
__device__ __forceinline__ unsigned pack2bf(float a, float b) {
    unsigned ua = __builtin_bit_cast(unsigned, a) + 0x8000u;
    unsigned ub = __builtin_bit_cast(unsigned, b) + 0x8000u;
#if __has_builtin(__builtin_amdgcn_perm)
    return __builtin_amdgcn_perm(ub, ua, 0x07060302u);  // {ub.hi16, ua.hi16}
#else
    return (ua >> 16) | (ub & 0xffff0000u);
#endif
}

// ---------- weights -> bf16 [320][256] + fp32 bias[320]; log2e folded into q ----------
__global__ __launch_bounds__(256) void cvt_w(
    const float* __restrict__ Wq, const float* __restrict__ bq,
    const float* __restrict__ Wk, const float* __restrict__ bk,
    const float* __restrict__ Wv, const float* __restrict__ bv,
    unsigned short* __restrict__ wbf, float* __restrict__ biasf)
{
    const float LOG2E = 1.4426950408889634f;
    const int r = blockIdx.x;   // 0..319
    const int t = threadIdx.x;
    const float* src = (r < 32) ? (Wq + r * C_)
                     : (r < 64) ? (Wk + (r - 32) * C_)
                                : (Wv + (r - 64) * C_);
    const float scale = (r < 32) ? LOG2E : 1.0f;
    wbf[r * C_ + t] = f2bf(src[t] * scale);
    if (t == 0)
        biasf[r] = (r < 32) ? bq[r] * LOG2E : (r < 64) ? bk[r - 32] : bv[r - 64];
}

// ---------- fused qkv projection: W-resident registers, x direct, LDS bounce for q/k ----------
// grid (N/32=128, B), 256 threads (4 waves). Wave w owns output rows 80w..80w+79.
__global__ __launch_bounds__(256, 2) void proj_qkv(
    const float* __restrict__ x, const unsigned short* __restrict__ wbf,
    const float* __restrict__ biasf,
    unsigned short* __restrict__ qb, unsigned short* __restrict__ kb,
    unsigned short* __restrict__ vb)
{
    __shared__ __align__(16) unsigned short qks[32 * 72];  // 4.6 KB: [n][q(0..31)|k(32..63)]

    const int t    = threadIdx.x;
    const int w    = t >> 6;
    const int lane = t & 63;
    const int quad = lane >> 4;
    const int c16  = lane & 15;
    const int n0   = blockIdx.x * 32;
    const int b    = blockIdx.y;

    f32x4 acc[5][2];
#pragma unroll
    for (int i = 0; i < 5; ++i)
#pragma unroll
        for (int nt = 0; nt < 2; ++nt) acc[i][nt] = (f32x4){0.f, 0.f, 0.f, 0.f};

    const float* xb = x + (size_t)(b * C_) * N_ + n0 + c16;
    const unsigned short* wr = wbf + (size_t)(80 * w + c16) * C_ + quad * 8;

#pragma unroll
    for (int h = 0; h < 2; ++h) {
        short8 af[5][4];   // W A-frags for this K-half (resident)
#pragma unroll
        for (int i = 0; i < 5; ++i)
#pragma unroll
            for (int k4 = 0; k4 < 4; ++k4)
                af[i][k4] = *(const short8*)(wr + (size_t)(16 * i) * C_ + 128 * h + 32 * k4);
#pragma unroll
        for (int k4 = 0; k4 < 4; ++k4) {
            short8 bf[2];
#pragma unroll
            for (int nt = 0; nt < 2; ++nt) {
                const float* xc = xb + (size_t)(128 * h + 32 * k4 + 8 * quad) * N_ + 16 * nt;
#pragma unroll
                for (int j = 0; j < 8; ++j)
                    bf[nt][j] = (short)f2bf(xc[(size_t)j * N_]);
            }
#pragma unroll
            for (int i = 0; i < 5; ++i)
#pragma unroll
                for (int nt = 0; nt < 2; ++nt)
                    acc[i][nt] = __builtin_amdgcn_mfma_f32_16x16x32_bf16(af[i][k4], bf[nt], acc[i][nt], 0, 0, 0);
        }
    }

    // ---- epilogue: v direct (n-contiguous); q/k via LDS bounce for full-line stores
#pragma unroll
    for (int i = 0; i < 5; ++i) {
        const int OT = 5 * w + i;
        const int obase = OT * 16 + 4 * quad;
        const f32x4 bv4 = *(const f32x4*)&biasf[obase];
#pragma unroll
        for (int nt = 0; nt < 2; ++nt) {
            const int n = n0 + 16 * nt + c16;
            float vals[4];
#pragma unroll
            for (int r = 0; r < 4; ++r) vals[r] = acc[i][nt][r] + bv4[r];
            if (OT >= 4) {      // v: [b][c][n]
#pragma unroll
                for (int r = 0; r < 4; ++r)
                    vb[((size_t)(b * C_) + obase + r - 64) * N_ + n] = f2bf(vals[r]);
            } else {            // q/k -> LDS tile (only wave 0 reaches here)
                const int row = 16 * nt + c16;
                const int col = (OT < 2 ? 0 : 32) + (OT & 1) * 16 + 4 * quad;
                short4v pk;
#pragma unroll
                for (int r = 0; r < 4; ++r) pk[r] = (short)f2bf(vals[r]);
                *(short4v*)&qks[row * 72 + col] = pk;
            }
        }
    }
    __syncthreads();
    if (w < 2) {   // wave0 -> q, wave1 -> k: 2 full-line 1KB stores each
        unsigned short* dst = w ? kb : qb;
        const int coff = w ? 32 : 0;
#pragma unroll
        for (int h = 0; h < 2; ++h) {
            const int n = 16 * h + (lane >> 2);
            const int c = (lane & 3) * 8;
            const short8 v = *(const short8*)&qks[n * 72 + coff + c];
            *(short8*)(dst + ((size_t)(b * N_) + n0 + n) * 32 + c) = v;
        }
    }
}

// ---------- flash attention: deferred l-reduce, exp2, ping-pong prefetch ----------
// 1-D grid of 512: b = flat&3 (XCD-affine), q0 = (flat>>2)*32; 256 threads (4 waves)
__global__ __launch_bounds__(256, 2) void attn_kernel(
    const float* __restrict__ x,
    const unsigned short* __restrict__ qg,
    const unsigned short* __restrict__ kg,
    const unsigned short* __restrict__ vg,
    float* __restrict__ out)
{
    __shared__ __align__(16) unsigned short ps[2][TQ * PSS];  // 9.2 KB
    __shared__ float ls[4 * TQ];

    const int t    = threadIdx.x;
    const int w    = t >> 6;        // S-phase kv-tile AND PV-phase c-group
    const int lane = t & 63;
    const int quad = lane >> 4;
    const int c16  = lane & 15;
    const int flat = blockIdx.x;
    const int b    = flat & 3;
    const int q0   = (flat >> 2) * TQ;
    const int kvc  = w * 16 + 4 * quad;

    const unsigned short* kbase = kg + (size_t)(b * N_) * 32;
    const unsigned short* vbase = vg + (size_t)(b * C_) * N_;

    // iter-invariant Q B-frags
    const short8 bq0 = *(const short8*)(qg + ((size_t)(b * N_) + q0 + c16) * 32 + quad * 8);
    const short8 bq1 = *(const short8*)(qg + ((size_t)(b * N_) + q0 + 16 + c16) * 32 + quad * 8);

    f32x4 O[4][2];
#pragma unroll
    for (int ct = 0; ct < 4; ++ct)
#pragma unroll
        for (int qt = 0; qt < 2; ++qt) O[ct][qt] = (f32x4){0.f, 0.f, 0.f, 0.f};

    float lacc0 = 0.f, lacc1 = 0.f;

    short8 akA, akB, avA[2][4], avB[2][4];
    // prefetch chunk 0 into set A
    akA = *(const short8*)(kbase + (size_t)(w * 16 + c16) * 32 + quad * 8);
#pragma unroll
    for (int s = 0; s < 2; ++s)
#pragma unroll
        for (int ct = 0; ct < 4; ++ct)
            avA[s][ct] = *(const short8*)(
                vbase + (size_t)(64 * w + 16 * ct + c16) * N_ + 32 * s + 8 * quad);

    auto chunk = [&](int ic, const short8& akc, const short8 (&avc)[2][4],
                     short8& akn, short8 (&avn)[2][4], int pb) {
        // prefetch next chunk (max distance to the barrier's vmcnt drain)
        const int icn = (ic + 1 < ITERS) ? ic + 1 : ITERS - 1;
        const size_t kvn = (size_t)icn * TM;
        akn = *(const short8*)(kbase + (kvn + w * 16 + c16) * 32 + quad * 8);
#pragma unroll
        for (int s = 0; s < 2; ++s)
#pragma unroll
            for (int ct = 0; ct < 4; ++ct)
                avn[s][ct] = *(const short8*)(
                    vbase + (size_t)(64 * w + 16 * ct + c16) * N_ + kvn + 32 * s + 8 * quad);

        // S^T = K.Q^T (lane: kv = 16w+4quad+r, q = 16g+c16); scores pre-scaled by log2e
        const f32x4 z = {0.f, 0.f, 0.f, 0.f};
        const f32x4 s0 = __builtin_amdgcn_mfma_f32_16x16x32_bf16(akc, bq0, z, 0, 0, 0);
        const f32x4 s1 = __builtin_amdgcn_mfma_f32_16x16x32_bf16(akc, bq1, z, 0, 0, 0);

        float p0[4], p1[4];
#pragma unroll
        for (int r = 0; r < 4; ++r) { p0[r] = EXP2F(s0[r]); p1[r] = EXP2F(s1[r]); }
        lacc0 += (p0[0] + p0[1]) + (p0[2] + p0[3]);   // off critical path
        lacc1 += (p1[0] + p1[1]) + (p1[2] + p1[3]);

        uint2v u0, u1;
        u0.x = pack2bf(p0[0], p0[1]); u0.y = pack2bf(p0[2], p0[3]);
        u1.x = pack2bf(p1[0], p1[1]); u1.y = pack2bf(p1[2], p1[3]);
        *(uint2v*)&ps[pb][c16 * PSS + kvc]        = u0;
        *(uint2v*)&ps[pb][(16 + c16) * PSS + kvc] = u1;

        __syncthreads();

        // PV: O^T[c][q] += V^T[c][kv] . P^T[kv][q]; wave owns c 64w..+63
        short8 bp[2][2];
#pragma unroll
        for (int qt = 0; qt < 2; ++qt)
#pragma unroll
            for (int s = 0; s < 2; ++s)
                bp[qt][s] = *(const short8*)&ps[pb][(16 * qt + c16) * PSS + 32 * s + 8 * quad];
#pragma unroll
        for (int s = 0; s < 2; ++s)
#pragma unroll
            for (int ct = 0; ct < 4; ++ct) {
                O[ct][0] = __builtin_amdgcn_mfma_f32_16x16x32_bf16(avc[s][ct], bp[0][s], O[ct][0], 0, 0, 0);
                O[ct][1] = __builtin_amdgcn_mfma_f32_16x16x32_bf16(avc[s][ct], bp[1][s], O[ct][1], 0, 0, 0);
            }
    };

#pragma unroll 1
    for (int ic = 0; ic < ITERS; ic += 2) {
        chunk(ic,     akA, avA, akB, avB, 0);
        chunk(ic + 1, akB, avB, akA, avA, 1);
    }

    // ---- deferred l reduction (once)
    lacc0 += __shfl_xor(lacc0, 16); lacc0 += __shfl_xor(lacc0, 32);
    lacc1 += __shfl_xor(lacc1, 16); lacc1 += __shfl_xor(lacc1, 32);
    if (quad == 0) {
        ls[w * TQ + c16]      = lacc0;
        ls[w * TQ + 16 + c16] = lacc1;
    }
    __syncthreads();

    // ---- epilogue: out = x + O / l
#pragma unroll
    for (int qt = 0; qt < 2; ++qt) {
        const int q = 16 * qt + c16;
        const float li = 1.0f / (ls[q] + ls[TQ + q] + ls[2 * TQ + q] + ls[3 * TQ + q]);
        const int n = q0 + q;
#pragma unroll
        for (int ct = 0; ct < 4; ++ct) {
#pragma unroll
            for (int r = 0; r < 4; ++r) {
                const int c = 64 * w + 16 * ct + 4 * quad + r;
                const size_t idx = ((size_t)(b * C_) + c) * N_ + n;
                out[idx] = x[idx] + O[ct][qt][r] * li;
            }
        }
    }
}

extern "C" void kernel_launch(void* const* d_in, const int* in_sizes, int n_in,
                              void* d_out, int out_size, void* d_ws, size_t ws_size,
                              hipStream_t stream) {
    const float* x  = (const float*)d_in[0];
    const float* Wq = (const float*)d_in[1];
    const float* bq = (const float*)d_in[2];
    const float* Wk = (const float*)d_in[3];
    const float* bk = (const float*)d_in[4];
    const float* Wv = (const float*)d_in[5];
    const float* bv = (const float*)d_in[6];
    float* out = (float*)d_out;

    unsigned short* ws16 = (unsigned short*)d_ws;
    unsigned short* qb  = ws16;                              // [B][N][32]  1 MB
    unsigned short* kb  = qb + (size_t)B_ * N_ * 32;         // [B][N][32]  1 MB
    unsigned short* vb  = kb + (size_t)B_ * N_ * 32;         // [B][C][N]   8 MB
    unsigned short* wbf = vb + (size_t)B_ * C_ * N_;         // [320][256] bf16
    float* biasf = (float*)(wbf + 320 * C_);                 // [320] fp32

    cvt_w<<<dim3(320), 256, 0, stream>>>(Wq, bq, Wk, bk, Wv, bv, wbf, biasf);
    proj_qkv<<<dim3(N_ / 32, B_), 256, 0, stream>>>(x, wbf, biasf, qb, kb, vb);
    attn_kernel<<<dim3(512), 256, 0, stream>>>(x, qb, kb, vb, out);
}

// Round 8
// 161.998 us; speedup vs baseline: 1.3966x; 1.3723x over previous
//
#include <hip/hip_runtime.h>
#include <math.h>

#define B_   4
#define C_   256
#define CQK  32
#define N_   4096
#define TQ   64
#define TM   64
#define ITERS (N_ / TM)
#define PSS  72   // ps row stride (shorts)

typedef __attribute__((ext_vector_type(8))) short short8;
typedef __attribute__((ext_vector_type(4))) short short4v;
typedef __attribute__((ext_vector_type(4))) float f32x4;
typedef __attribute__((ext_vector_type(2))) unsigned int uint2v;

#if __has_builtin(__builtin_amdgcn_exp2f)
#define EXP2F(x) __builtin_amdgcn_exp2f(x)
#else
#define EXP2F(x) exp2f(x)
#endif

__device__ __forceinline__ unsigned short f2bf(float f) {
    unsigned u = __builtin_bit_cast(unsigned, f);
    u += 0x7fffu + ((u >> 16) & 1u);
    return (unsigned short)(u >> 16);
}

__device__ __forceinline__ unsigned pack2bf(float a, float b) {
    unsigned ua = __builtin_bit_cast(unsigned, a) + 0x8000u;
    unsigned ub = __builtin_bit_cast(unsigned, b) + 0x8000u;
#if __has_builtin(__builtin_amdgcn_perm)
    return __builtin_amdgcn_perm(ub, ua, 0x07060302u);
#else
    return (ua >> 16) | (ub & 0xffff0000u);
#endif
}

// ---------- weights -> bf16 [320][256] + fp32 bias[320]; log2e folded into q ----------
__global__ __launch_bounds__(256) void cvt_w(
    const float* __restrict__ Wq, const float* __restrict__ bq,
    const float* __restrict__ Wk, const float* __restrict__ bk,
    const float* __restrict__ Wv, const float* __restrict__ bv,
    unsigned short* __restrict__ wbf, float* __restrict__ biasf)
{
    const float LOG2E = 1.4426950408889634f;
    const int r = blockIdx.x;   // 0..319
    const int t = threadIdx.x;
    const float* src = (r < 32) ? (Wq + r * C_)
                     : (r < 64) ? (Wk + (r - 32) * C_)
                                : (Wv + (r - 64) * C_);
    const float scale = (r < 32) ? LOG2E : 1.0f;
    wbf[r * C_ + t] = f2bf(src[t] * scale);
    if (t == 0)
        biasf[r] = (r < 32) ? bq[r] * LOG2E : (r < 64) ? bk[r - 32] : bv[r - 64];
}

// ---------- fused qkv projection (unchanged from R7) ----------
__global__ __launch_bounds__(256, 2) void proj_qkv(
    const float* __restrict__ x, const unsigned short* __restrict__ wbf,
    const float* __restrict__ biasf,
    unsigned short* __restrict__ qb, unsigned short* __restrict__ kb,
    unsigned short* __restrict__ vb)
{
    __shared__ __align__(16) unsigned short qks[32 * 72];

    const int t    = threadIdx.x;
    const int w    = t >> 6;
    const int lane = t & 63;
    const int quad = lane >> 4;
    const int c16  = lane & 15;
    const int n0   = blockIdx.x * 32;
    const int b    = blockIdx.y;

    f32x4 acc[5][2];
#pragma unroll
    for (int i = 0; i < 5; ++i)
#pragma unroll
        for (int nt = 0; nt < 2; ++nt) acc[i][nt] = (f32x4){0.f, 0.f, 0.f, 0.f};

    const float* xb = x + (size_t)(b * C_) * N_ + n0 + c16;
    const unsigned short* wr = wbf + (size_t)(80 * w + c16) * C_ + quad * 8;

#pragma unroll
    for (int h = 0; h < 2; ++h) {
        short8 af[5][4];
#pragma unroll
        for (int i = 0; i < 5; ++i)
#pragma unroll
            for (int k4 = 0; k4 < 4; ++k4)
                af[i][k4] = *(const short8*)(wr + (size_t)(16 * i) * C_ + 128 * h + 32 * k4);
#pragma unroll
        for (int k4 = 0; k4 < 4; ++k4) {
            short8 bf[2];
#pragma unroll
            for (int nt = 0; nt < 2; ++nt) {
                const float* xc = xb + (size_t)(128 * h + 32 * k4 + 8 * quad) * N_ + 16 * nt;
#pragma unroll
                for (int j = 0; j < 8; ++j)
                    bf[nt][j] = (short)f2bf(xc[(size_t)j * N_]);
            }
#pragma unroll
            for (int i = 0; i < 5; ++i)
#pragma unroll
                for (int nt = 0; nt < 2; ++nt)
                    acc[i][nt] = __builtin_amdgcn_mfma_f32_16x16x32_bf16(af[i][k4], bf[nt], acc[i][nt], 0, 0, 0);
        }
    }

#pragma unroll
    for (int i = 0; i < 5; ++i) {
        const int OT = 5 * w + i;
        const int obase = OT * 16 + 4 * quad;
        const f32x4 bv4 = *(const f32x4*)&biasf[obase];
#pragma unroll
        for (int nt = 0; nt < 2; ++nt) {
            const int n = n0 + 16 * nt + c16;
            float vals[4];
#pragma unroll
            for (int r = 0; r < 4; ++r) vals[r] = acc[i][nt][r] + bv4[r];
            if (OT >= 4) {
#pragma unroll
                for (int r = 0; r < 4; ++r)
                    vb[((size_t)(b * C_) + obase + r - 64) * N_ + n] = f2bf(vals[r]);
            } else {
                const int row = 16 * nt + c16;
                const int col = (OT < 2 ? 0 : 32) + (OT & 1) * 16 + 4 * quad;
                short4v pk;
#pragma unroll
                for (int r = 0; r < 4; ++r) pk[r] = (short)f2bf(vals[r]);
                *(short4v*)&qks[row * 72 + col] = pk;
            }
        }
    }
    __syncthreads();
    if (w < 2) {
        unsigned short* dst = w ? kb : qb;
        const int coff = w ? 32 : 0;
#pragma unroll
        for (int h = 0; h < 2; ++h) {
            const int n = 16 * h + (lane >> 2);
            const int c = (lane & 3) * 8;
            const short8 v = *(const short8*)&qks[n * 72 + coff + c];
            *(short8*)(dst + ((size_t)(b * N_) + n0 + n) * 32 + c) = v;
        }
    }
}

// ---------- flash attention: TQ=64, 4 waves, V read once per block ----------
// grid 256: b = flat&3 (XCD-affine), q0 = (flat>>2)*64
__global__ __launch_bounds__(256, 1) void attn_kernel(
    const float* __restrict__ x,
    const unsigned short* __restrict__ qg,
    const unsigned short* __restrict__ kg,
    const unsigned short* __restrict__ vg,
    float* __restrict__ out)
{
    __shared__ __align__(16) unsigned short ps[2][TQ * PSS];  // 18.4 KB
    __shared__ float ls[4 * TQ];

    const int t    = threadIdx.x;
    const int w    = t >> 6;        // S-phase kv-tile AND PV-phase c-stripe
    const int lane = t & 63;
    const int quad = lane >> 4;
    const int c16  = lane & 15;
    const int b    = blockIdx.x & 3;
    const int q0   = (blockIdx.x >> 2) * TQ;
    const int kvc  = w * 16 + 4 * quad;

    const unsigned short* kbase = kg + (size_t)(b * N_) * 32;
    const unsigned short* vbase = vg + (size_t)(b * C_) * N_;

    // iter-invariant Q B-frags (4 q-tiles)
    short8 bq[4];
#pragma unroll
    for (int g = 0; g < 4; ++g)
        bq[g] = *(const short8*)(qg + ((size_t)(b * N_) + q0 + 16 * g + c16) * 32 + quad * 8);

    f32x4 O[4][4];   // [c-tile][q-tile]
#pragma unroll
    for (int ct = 0; ct < 4; ++ct)
#pragma unroll
        for (int qt = 0; qt < 4; ++qt) O[ct][qt] = (f32x4){0.f, 0.f, 0.f, 0.f};

    float lacc[4] = {0.f, 0.f, 0.f, 0.f};

    short8 akA, akB, avA[2][4], avB[2][4];
    akA = *(const short8*)(kbase + (size_t)(w * 16 + c16) * 32 + quad * 8);
#pragma unroll
    for (int s = 0; s < 2; ++s)
#pragma unroll
        for (int ct = 0; ct < 4; ++ct)
            avA[s][ct] = *(const short8*)(
                vbase + (size_t)(64 * w + 16 * ct + c16) * N_ + 32 * s + 8 * quad);

    auto chunk = [&](int ic, const short8& akc, const short8 (&avc)[2][4],
                     short8& akn, short8 (&avn)[2][4], int pb) {
        // prefetch next chunk (drained by the barrier's vmcnt(0))
        const int icn = (ic + 1 < ITERS) ? ic + 1 : ITERS - 1;
        const size_t kvn = (size_t)icn * TM;
        akn = *(const short8*)(kbase + (kvn + w * 16 + c16) * 32 + quad * 8);
#pragma unroll
        for (int s = 0; s < 2; ++s)
#pragma unroll
            for (int ct = 0; ct < 4; ++ct)
                avn[s][ct] = *(const short8*)(
                    vbase + (size_t)(64 * w + 16 * ct + c16) * N_ + kvn + 32 * s + 8 * quad);

        // S^T = K.Q^T for 4 q-tiles (lane: kv = 16w+4quad+r, q = 16g+c16)
        const f32x4 z = {0.f, 0.f, 0.f, 0.f};
        f32x4 sf[4];
#pragma unroll
        for (int g = 0; g < 4; ++g)
            sf[g] = __builtin_amdgcn_mfma_f32_16x16x32_bf16(akc, bq[g], z, 0, 0, 0);

        // exp2 (log2e pre-folded), defer l, pack P^T -> LDS
#pragma unroll
        for (int g = 0; g < 4; ++g) {
            float p[4];
#pragma unroll
            for (int r = 0; r < 4; ++r) p[r] = EXP2F(sf[g][r]);
            lacc[g] += (p[0] + p[1]) + (p[2] + p[3]);
            uint2v u;
            u.x = pack2bf(p[0], p[1]);
            u.y = pack2bf(p[2], p[3]);
            *(uint2v*)&ps[pb][(16 * g + c16) * PSS + kvc] = u;
        }

        __syncthreads();

        // PV: wave owns c 64w..+63, serves ALL 64 q
        short8 bp[4][2];
#pragma unroll
        for (int qt = 0; qt < 4; ++qt)
#pragma unroll
            for (int s = 0; s < 2; ++s)
                bp[qt][s] = *(const short8*)&ps[pb][(16 * qt + c16) * PSS + 32 * s + 8 * quad];
#pragma unroll
        for (int s = 0; s < 2; ++s)
#pragma unroll
            for (int ct = 0; ct < 4; ++ct)
#pragma unroll
                for (int qt = 0; qt < 4; ++qt)
                    O[ct][qt] = __builtin_amdgcn_mfma_f32_16x16x32_bf16(avc[s][ct], bp[qt][s], O[ct][qt], 0, 0, 0);
    };

#pragma unroll 1
    for (int ic = 0; ic < ITERS; ic += 2) {
        chunk(ic,     akA, avA, akB, avB, 0);
        chunk(ic + 1, akB, avB, akA, avA, 1);
    }

    // deferred l reduction
#pragma unroll
    for (int g = 0; g < 4; ++g) {
        lacc[g] += __shfl_xor(lacc[g], 16);
        lacc[g] += __shfl_xor(lacc[g], 32);
    }
    if (quad == 0) {
#pragma unroll
        for (int g = 0; g < 4; ++g)
            ls[w * TQ + 16 * g + c16] = lacc[g];
    }
    __syncthreads();

    // epilogue: out = x + O / l
#pragma unroll
    for (int qt = 0; qt < 4; ++qt) {
        const int q = 16 * qt + c16;
        const float li = 1.0f / (ls[q] + ls[TQ + q] + ls[2 * TQ + q] + ls[3 * TQ + q]);
        const int n = q0 + q;
#pragma unroll
        for (int ct = 0; ct < 4; ++ct) {
#pragma unroll
            for (int r = 0; r < 4; ++r) {
                const int c = 64 * w + 16 * ct + 4 * quad + r;
                const size_t idx = ((size_t)(b * C_) + c) * N_ + n;
                out[idx] = x[idx] + O[ct][qt][r] * li;
            }
        }
    }
}

extern "C" void kernel_launch(void* const* d_in, const int* in_sizes, int n_in,
                              void* d_out, int out_size, void* d_ws, size_t ws_size,
                              hipStream_t stream) {
    const float* x  = (const float*)d_in[0];
    const float* Wq = (const float*)d_in[1];
    const float* bq = (const float*)d_in[2];
    const float* Wk = (const float*)d_in[3];
    const float* bk = (const float*)d_in[4];
    const float* Wv = (const float*)d_in[5];
    const float* bv = (const float*)d_in[6];
    float* out = (float*)d_out;

    unsigned short* ws16 = (unsigned short*)d_ws;
    unsigned short* qb  = ws16;                              // [B][N][32]  1 MB
    unsigned short* kb  = qb + (size_t)B_ * N_ * 32;         // [B][N][32]  1 MB
    unsigned short* vb  = kb + (size_t)B_ * N_ * 32;         // [B][C][N]   8 MB
    unsigned short* wbf = vb + (size_t)B_ * C_ * N_;         // [320][256] bf16
    float* biasf = (float*)(wbf + 320 * C_);                 // [320] fp32

    cvt_w<<<dim3(320), 256, 0, stream>>>(Wq, bq, Wk, bk, Wv, bv, wbf, biasf);
    proj_qkv<<<dim3(N_ / 32, B_), 256, 0, stream>>>(x, wbf, biasf, qb, kb, vb);
    attn_kernel<<<dim3(N_ / TQ * B_), 256, 0, stream>>>(x, qb, kb, vb, out);
}

// Round 10
// 155.035 us; speedup vs baseline: 1.4593x; 1.0449x over previous
//
#include <hip/hip_runtime.h>
#include <math.h>

#define B_   4
#define C_   256
#define CQK  32
#define N_   4096
#define TQ   128          // q per attn block
#define TM   64           // kv per chunk
#define HITERS ((N_ / 2) / TM)   // 32 chunks per kv-half
#define PSS  72           // ps row stride (shorts)
#define XTS  264          // proj xT row stride (shorts): 256 + 8 pad, 528B rows

typedef __attribute__((ext_vector_type(8))) short short8;
typedef __attribute__((ext_vector_type(4))) short short4v;
typedef __attribute__((ext_vector_type(4))) float f32x4;
typedef __attribute__((ext_vector_type(2))) unsigned int uint2v;

#if __has_builtin(__builtin_amdgcn_exp2f)
#define EXP2F(x) __builtin_amdgcn_exp2f(x)
#else
#define EXP2F(x) exp2f(x)
#endif

__device__ __forceinline__ unsigned short f2bf(float f) {
    unsigned u = __builtin_bit_cast(unsigned, f);
    u += 0x7fffu + ((u >> 16) & 1u);
    return (unsigned short)(u >> 16);
}
__device__ __forceinline__ float bf2f(unsigned short s) {
    return __builtin_bit_cast(float, (unsigned)s << 16);
}
__device__ __forceinline__ unsigned pack2bf(float a, float b) {
    unsigned ua = __builtin_bit_cast(unsigned, a) + 0x8000u;
    unsigned ub = __builtin_bit_cast(unsigned, b) + 0x8000u;
#if __has_builtin(__builtin_amdgcn_perm)
    return __builtin_amdgcn_perm(ub, ua, 0x07060302u);
#else
    return (ua >> 16) | (ub & 0xffff0000u);
#endif
}

// ---------- weights -> bf16 [320][256] + fp32 bias[320]; log2e folded into q ----------
__global__ __launch_bounds__(256) void cvt_w(
    const float* __restrict__ Wq, const float* __restrict__ bq,
    const float* __restrict__ Wk, const float* __restrict__ bk,
    const float* __restrict__ Wv, const float* __restrict__ bv,
    unsigned short* __restrict__ wbf, float* __restrict__ biasf)
{
    const float LOG2E = 1.4426950408889634f;
    const int r = blockIdx.x;   // 0..319
    const int t = threadIdx.x;
    const float* src = (r < 32) ? (Wq + r * C_)
                     : (r < 64) ? (Wk + (r - 32) * C_)
                                : (Wv + (r - 64) * C_);
    const float scale = (r < 32) ? LOG2E : 1.0f;
    wbf[r * C_ + t] = f2bf(src[t] * scale);
    if (t == 0)
        biasf[r] = (r < 32) ? bq[r] * LOG2E : (r < 64) ? bk[r - 32] : bv[r - 64];
}

// ---------- fused qkv projection: coalesced x staging + LDS transpose ----------
// grid (N/64 = 64, B), 256 threads (4 waves). Wave w: output rows 80w..80w+79, all 64 n.
__global__ __launch_bounds__(256, 2) void proj_qkv(
    const float* __restrict__ x, const unsigned short* __restrict__ wbf,
    const float* __restrict__ biasf,
    unsigned short* __restrict__ qb, unsigned short* __restrict__ kb,
    unsigned short* __restrict__ vb)
{
    __shared__ __align__(16) unsigned short xT[64 * XTS];  // 33.8 KB [n][c] bf16
    __shared__ __align__(16) unsigned short qks[64 * 72];  //  9.2 KB

    const int t    = threadIdx.x;
    const int w    = t >> 6;
    const int lane = t & 63;
    const int quad = lane >> 4;
    const int c16  = lane & 15;
    const int n0   = blockIdx.x * 64;
    const int b    = blockIdx.y;

    // stage x tile (256c x 64n fp32) with coalesced float4 loads, transpose to bf16
#pragma unroll
    for (int p = 0; p < 16; ++p) {
        const int c  = (t >> 2) + 64 * (p >> 2);
        const int nq = (t & 3) + 4 * (p & 3);
        const f32x4 xv = *(const f32x4*)&x[((size_t)(b * C_) + c) * N_ + n0 + 4 * nq];
#pragma unroll
        for (int j = 0; j < 4; ++j)
            xT[(4 * nq + j) * XTS + c] = f2bf(xv[j]);
    }
    __syncthreads();

    f32x4 acc[5][4];
#pragma unroll
    for (int i = 0; i < 5; ++i)
#pragma unroll
        for (int nt = 0; nt < 4; ++nt) acc[i][nt] = (f32x4){0.f, 0.f, 0.f, 0.f};

    const unsigned short* wr = wbf + (size_t)(80 * w + c16) * C_ + quad * 8;

#pragma unroll
    for (int ks = 0; ks < 8; ++ks) {
        short8 af[5], bf[4];
#pragma unroll
        for (int i = 0; i < 5; ++i)
            af[i] = *(const short8*)(wr + (size_t)(16 * i) * C_ + 32 * ks);
#pragma unroll
        for (int nt = 0; nt < 4; ++nt)
            bf[nt] = *(const short8*)&xT[(16 * nt + c16) * XTS + ks * 32 + quad * 8];
#pragma unroll
        for (int i = 0; i < 5; ++i)
#pragma unroll
            for (int nt = 0; nt < 4; ++nt)
                acc[i][nt] = __builtin_amdgcn_mfma_f32_16x16x32_bf16(af[i], bf[nt], acc[i][nt], 0, 0, 0);
    }

#pragma unroll
    for (int i = 0; i < 5; ++i) {
        const int OT = 5 * w + i;
        const int obase = OT * 16 + 4 * quad;
        const f32x4 bv4 = *(const f32x4*)&biasf[obase];
#pragma unroll
        for (int nt = 0; nt < 4; ++nt) {
            const int n = n0 + 16 * nt + c16;
            float vals[4];
#pragma unroll
            for (int r = 0; r < 4; ++r) vals[r] = acc[i][nt][r] + bv4[r];
            if (OT >= 4) {      // v: [b][c][n]
#pragma unroll
                for (int r = 0; r < 4; ++r)
                    vb[((size_t)(b * C_) + obase + r - 64) * N_ + n] = f2bf(vals[r]);
            } else {            // q/k -> LDS tile (wave 0 only)
                const int row = 16 * nt + c16;
                const int col = (OT < 2 ? 0 : 32) + (OT & 1) * 16 + 4 * quad;
                short4v pk;
#pragma unroll
                for (int r = 0; r < 4; ++r) pk[r] = (short)f2bf(vals[r]);
                *(short4v*)&qks[row * 72 + col] = pk;
            }
        }
    }
    __syncthreads();
    if (w < 2) {   // wave0 -> q, wave1 -> k
        unsigned short* dst = w ? kb : qb;
        const int coff = w ? 32 : 0;
#pragma unroll
        for (int h = 0; h < 4; ++h) {
            const int n = 16 * h + (lane >> 2);
            const int c = (lane & 3) * 8;
            const short8 v = *(const short8*)&qks[n * 72 + coff + c];
            *(short8*)(dst + ((size_t)(b * N_) + n0 + n) * 32 + c) = v;
        }
    }
}

// ---------- flash attention: TQ=128, LDS-shared KV, split-kv 2-way ----------
// grid 256: half = flat&1, b = (flat>>1)&3, q0 = (flat>>3)*128 (XCD-affine in (half,b))
// half 0 -> fp32 partial into `outp` (layout [B][C][N]); half 1 -> bf16 partial Op1
__global__ __launch_bounds__(512, 1) void attn_kernel(
    const unsigned short* __restrict__ qg,
    const unsigned short* __restrict__ kg,
    const unsigned short* __restrict__ vg,
    float* __restrict__ outp,          // [B][C][N] fp32 partial (half 0)
    unsigned short* __restrict__ Op1,  // [B][C][N] bf16 partial (half 1)
    float* __restrict__ lp)            // [2][B][N] fp32 l partials
{
    __shared__ __align__(16) unsigned short ks[TM * 40];    //  5.1 KB [kv][c]
    __shared__ __align__(16) unsigned short vs[C_ * TM];    // 32.0 KB [c][kv] swizzled
    __shared__ __align__(16) unsigned short ps[TQ * PSS];   // 18.4 KB [q][kv]
    __shared__ float ls[4 * TQ];                            //  2.0 KB

    const int t    = threadIdx.x;
    const int w    = t >> 6;
    const int lane = t & 63;
    const int quad = lane >> 4;
    const int c16  = lane & 15;
    const int flat = blockIdx.x;
    const int half = flat & 1;
    const int b    = (flat >> 1) & 3;
    const int q0   = (flat >> 3) * TQ;
    const int kvb0 = half * (N_ / 2);
    // S-phase roles
    const int f   = w & 3;      // kv-tile
    const int qg_ = w >> 2;     // q-group: q-tiles 4qg_..4qg_+3
    // PV roles
    const int cs = w & 3;       // c-stripe (64 c)
    const int pg = w >> 2;      // q-group (64 q)

    const unsigned short* kbase = kg + (size_t)(b * N_) * 32;
    const unsigned short* vbase = vg + (size_t)(b * C_) * N_;

    // hoisted Q B-frags
    short8 bq[4];
#pragma unroll
    for (int g = 0; g < 4; ++g)
        bq[g] = *(const short8*)(qg + ((size_t)(b * N_) + q0 + 16 * (4 * qg_ + g) + c16) * 32 + quad * 8);

    // staging assignment: V: c-row = t>>3 (+64p), kv-seg = t&7 ; K (t<256): row t>>2, seg t&3
    const int vc0 = t >> 3, vj = t & 7;
    const int kn = t >> 2, kseg = t & 3;

    short8 vpre[4], kpre;
#pragma unroll
    for (int p = 0; p < 4; ++p)
        vpre[p] = *(const short8*)(vbase + (size_t)(vc0 + 64 * p) * N_ + kvb0 + vj * 8);
    if (t < 256)
        kpre = *(const short8*)(kbase + (size_t)(kvb0 + kn) * 32 + kseg * 8);

    f32x4 O[4][4];
#pragma unroll
    for (int ct = 0; ct < 4; ++ct)
#pragma unroll
        for (int qt = 0; qt < 4; ++qt) O[ct][qt] = (f32x4){0.f, 0.f, 0.f, 0.f};

    float lacc[4] = {0.f, 0.f, 0.f, 0.f};

#pragma unroll 1
    for (int it = 0; it < HITERS; ++it) {
        // (1) regs -> LDS
#pragma unroll
        for (int p = 0; p < 4; ++p) {
            const int c = vc0 + 64 * p;
            *(short8*)&vs[c * TM + 8 * (vj ^ (c & 7))] = vpre[p];
        }
        if (t < 256)
            *(short8*)&ks[kn * 40 + kseg * 8] = kpre;
        __syncthreads();   // A: KV visible

        // (2) S^T = K.Q^T for 4 q-tiles
        const short8 ak = *(const short8*)&ks[(16 * f + c16) * 40 + quad * 8];
        const f32x4 z = {0.f, 0.f, 0.f, 0.f};
        f32x4 sf[4];
#pragma unroll
        for (int g = 0; g < 4; ++g)
            sf[g] = __builtin_amdgcn_mfma_f32_16x16x32_bf16(ak, bq[g], z, 0, 0, 0);

#pragma unroll
        for (int g = 0; g < 4; ++g) {
            float p[4];
#pragma unroll
            for (int r = 0; r < 4; ++r) p[r] = EXP2F(sf[g][r]);
            lacc[g] += (p[0] + p[1]) + (p[2] + p[3]);
            uint2v u;
            u.x = pack2bf(p[0], p[1]);
            u.y = pack2bf(p[2], p[3]);
            *(uint2v*)&ps[(16 * (4 * qg_ + g) + c16) * PSS + f * 16 + 4 * quad] = u;
        }
        __syncthreads();   // B: P visible

        // (3) PV; issue next chunk's global loads first (waited at their LDS-write use)
        if (it < HITERS - 1) {
            const int kv0n = kvb0 + (it + 1) * TM;
#pragma unroll
            for (int p = 0; p < 4; ++p)
                vpre[p] = *(const short8*)(vbase + (size_t)(vc0 + 64 * p) * N_ + kv0n + vj * 8);
            if (t < 256)
                kpre = *(const short8*)(kbase + (size_t)(kv0n + kn) * 32 + kseg * 8);
        }

        short8 bp[4][2];
#pragma unroll
        for (int qt = 0; qt < 4; ++qt)
#pragma unroll
            for (int s = 0; s < 2; ++s)
                bp[qt][s] = *(const short8*)&ps[(64 * pg + 16 * qt + c16) * PSS + 32 * s + 8 * quad];
#pragma unroll
        for (int s = 0; s < 2; ++s)
#pragma unroll
            for (int ct = 0; ct < 4; ++ct) {
                const int c = 64 * cs + 16 * ct + c16;
                const short8 av = *(const short8*)&vs[c * TM + 8 * ((4 * s + quad) ^ (c & 7))];
#pragma unroll
                for (int qt = 0; qt < 4; ++qt)
                    O[ct][qt] = __builtin_amdgcn_mfma_f32_16x16x32_bf16(av, bp[qt][s], O[ct][qt], 0, 0, 0);
            }
        __syncthreads();   // C: PV reads done; safe to overwrite LDS
    }

    // deferred l reduction (sum over quads per kv-tile)
#pragma unroll
    for (int g = 0; g < 4; ++g) {
        lacc[g] += __shfl_xor(lacc[g], 16);
        lacc[g] += __shfl_xor(lacc[g], 32);
    }
    if (quad == 0) {
#pragma unroll
        for (int g = 0; g < 4; ++g)
            ls[f * TQ + 16 * (4 * qg_ + g) + c16] = lacc[g];
    }
    __syncthreads();

    // store partials: half 0 -> fp32 into outp; half 1 -> bf16 into Op1
    if (half == 0) {
        float* ob = outp + (size_t)(b * C_) * N_;
#pragma unroll
        for (int ct = 0; ct < 4; ++ct)
#pragma unroll
            for (int qt = 0; qt < 4; ++qt) {
                const int n = q0 + 64 * pg + 16 * qt + c16;
#pragma unroll
                for (int r = 0; r < 4; ++r) {
                    const int c = 64 * cs + 16 * ct + 4 * quad + r;
                    ob[(size_t)c * N_ + n] = O[ct][qt][r];
                }
            }
    } else {
        unsigned short* ob = Op1 + (size_t)(b * C_) * N_;
#pragma unroll
        for (int ct = 0; ct < 4; ++ct)
#pragma unroll
            for (int qt = 0; qt < 4; ++qt) {
                const int n = q0 + 64 * pg + 16 * qt + c16;
#pragma unroll
                for (int r = 0; r < 4; ++r) {
                    const int c = 64 * cs + 16 * ct + 4 * quad + r;
                    ob[(size_t)c * N_ + n] = f2bf(O[ct][qt][r]);
                }
            }
    }
    if (cs == 0) {
        const int qq = 64 * pg + lane;
        const float lv = ls[qq] + ls[TQ + qq] + ls[2 * TQ + qq] + ls[3 * TQ + qq];
        lp[(size_t)(half * B_ + b) * N_ + q0 + qq] = lv;
    }
}

// ---------- combine: out = x + (O0(out) + O1) / (l0 + l1), in place ----------
// grid (N/1024 = 4, C/8 = 32, B), 256 threads
__global__ __launch_bounds__(256) void combine_kernel(
    const float* __restrict__ x,
    const unsigned short* __restrict__ Op1,
    const float* __restrict__ lp,
    float* __restrict__ out)
{
    __shared__ float linv[1024];

    const int t  = threadIdx.x;
    const int n0 = blockIdx.x * 1024;
    const int c0 = blockIdx.y * 8;
    const int b  = blockIdx.z;

#pragma unroll
    for (int i = 0; i < 4; ++i) {
        const int n = n0 + t + 256 * i;
        const float l = lp[(size_t)b * N_ + n] + lp[(size_t)(B_ + b) * N_ + n];
        linv[t + 256 * i] = 1.0f / l;
    }
    __syncthreads();

#pragma unroll
    for (int cc = 0; cc < 8; ++cc) {
        const int c = c0 + cc;
        const size_t base = ((size_t)(b * C_) + c) * N_ + n0 + 4 * t;
        const f32x4 o0 = *(const f32x4*)&out[base];
        const short4v a1 = *(const short4v*)&Op1[base];
        const f32x4 xv = *(const f32x4*)&x[base];
        f32x4 o;
        o.x = xv.x + (o0.x + bf2f((unsigned short)a1[0])) * linv[4 * t + 0];
        o.y = xv.y + (o0.y + bf2f((unsigned short)a1[1])) * linv[4 * t + 1];
        o.z = xv.z + (o0.z + bf2f((unsigned short)a1[2])) * linv[4 * t + 2];
        o.w = xv.w + (o0.w + bf2f((unsigned short)a1[3])) * linv[4 * t + 3];
        *(f32x4*)&out[base] = o;
    }
}

extern "C" void kernel_launch(void* const* d_in, const int* in_sizes, int n_in,
                              void* d_out, int out_size, void* d_ws, size_t ws_size,
                              hipStream_t stream) {
    const float* x  = (const float*)d_in[0];
    const float* Wq = (const float*)d_in[1];
    const float* bq = (const float*)d_in[2];
    const float* Wk = (const float*)d_in[3];
    const float* bk = (const float*)d_in[4];
    const float* Wv = (const float*)d_in[5];
    const float* bv = (const float*)d_in[6];
    float* out = (float*)d_out;

    unsigned short* ws16 = (unsigned short*)d_ws;
    unsigned short* qb  = ws16;                              // [B][N][32]   1 MB
    unsigned short* kb  = qb + (size_t)B_ * N_ * 32;         // [B][N][32]   1 MB
    unsigned short* vb  = kb + (size_t)B_ * N_ * 32;         // [B][C][N]    8 MB
    unsigned short* Op1 = vb + (size_t)B_ * C_ * N_;         // [B][C][N]    8 MB (bf16 partial, half 1)
    unsigned short* wbf = Op1 + (size_t)B_ * C_ * N_;        // [320][256]   160 KB
    float* biasf = (float*)(wbf + 320 * C_);                 // [320]
    float* lpp   = biasf + 320;                              // [2][B][N]    128 KB

    cvt_w<<<dim3(320), 256, 0, stream>>>(Wq, bq, Wk, bk, Wv, bv, wbf, biasf);
    proj_qkv<<<dim3(N_ / 64, B_), 256, 0, stream>>>(x, wbf, biasf, qb, kb, vb);
    attn_kernel<<<dim3(256), 512, 0, stream>>>(qb, kb, vb, out, Op1, lpp);
    combine_kernel<<<dim3(4, 32, B_), 256, 0, stream>>>(x, Op1, lpp, out);
}